// Round 1
// baseline (2344.056 us; speedup 1.0000x reference)
//
#include <hip/hip_runtime.h>

#define DEVFN static __device__ __forceinline__

DEVFN float leaky(float x) { return x > 0.f ? x : 0.01f * x; }

DEVFN float bcast(float v, int lane) {
    return __int_as_float(__builtin_amdgcn_readlane(__float_as_int(v), lane));
}

DEVFN float wsum(float v) {
#pragma unroll
    for (int o = 32; o > 0; o >>= 1) v += __shfl_xor(v, o, 64);
    return v;
}

// ---------------- scatter data_x into agg over dt edges ----------------
__global__ void k_scatter(const float* __restrict__ data_x,
                          const int* __restrict__ src, const int* __restrict__ dst,
                          float* __restrict__ agg, int n_edges) {
    int i = blockIdx.x * blockDim.x + threadIdx.x;
    if (i >= n_edges) return;
    int s = src[i], d = dst[i];
    const float* xp = data_x + (size_t)s * 5;
    float* ap = agg + (size_t)d * 5;
#pragma unroll
    for (int k = 0; k < 5; ++k) atomicAdd(ap + k, xp[k]);
}

// ---------------- fused = leaky(LN(agg@Wrel + brel + tasks@Wroot)) ----------------
__global__ void k_fused(const float* __restrict__ agg, const float* __restrict__ tasks_x,
                        const float* __restrict__ Wrel, const float* __restrict__ brel,
                        const float* __restrict__ Wroot,
                        const float* __restrict__ g, const float* __restrict__ b,
                        float* __restrict__ fused, int n_rows) {
    int lane = threadIdx.x & 63;
    int wave = (blockIdx.x * blockDim.x + threadIdx.x) >> 6;
    int nwaves = (gridDim.x * blockDim.x) >> 6;
    float wrel[5], wroot[12];
#pragma unroll
    for (int k = 0; k < 5; ++k) wrel[k] = Wrel[k * 64 + lane];
#pragma unroll
    for (int k = 0; k < 12; ++k) wroot[k] = Wroot[k * 64 + lane];
    float bj = brel[lane], gj = g[lane], bbj = b[lane];
    for (int r = wave; r < n_rows; r += nwaves) {
        float f = bj;
#pragma unroll
        for (int k = 0; k < 5; ++k) f = fmaf(agg[(size_t)r * 5 + k], wrel[k], f);
#pragma unroll
        for (int k = 0; k < 12; ++k) f = fmaf(tasks_x[(size_t)r * 12 + k], wroot[k], f);
        float m = wsum(f) * 0.015625f;
        float d = f - m;
        float v = wsum(d * d) * 0.015625f;
        float y = fmaf(d * rsqrtf(v + 1e-5f), gj, bbj);
        fused[(size_t)r * 64 + lane] = leaky(y);
    }
}

// ---------------- EdgeConv: per edge, u = leaky([xi, xj-xi]@W1+b1); o = u@W2+b2; scatter to dst ----
// wave-per-edge; lane j owns output column j; weight columns in VGPRs; x broadcast via readlane
__global__ void __launch_bounds__(256, 2) k_edgeconv(
    const float* __restrict__ x,
    const int* __restrict__ src, const int* __restrict__ dst,
    const float* __restrict__ W1, const float* __restrict__ b1,
    const float* __restrict__ W2, const float* __restrict__ b2,
    float* __restrict__ raw, int n_edges) {
    int lane = threadIdx.x & 63;
    int wave = (blockIdx.x * blockDim.x + threadIdx.x) >> 6;
    int nwaves = (gridDim.x * blockDim.x) >> 6;
    float w1a[64], w1b[64], w2[64];
#pragma unroll
    for (int k = 0; k < 64; ++k) w1a[k] = W1[k * 64 + lane];
#pragma unroll
    for (int k = 0; k < 64; ++k) w1b[k] = W1[(64 + k) * 64 + lane];
#pragma unroll
    for (int k = 0; k < 64; ++k) w2[k] = W2[k * 64 + lane];
    float b1j = b1[lane], b2j = b2[lane];
    for (int e = wave; e < n_edges; e += nwaves) {
        int s = src[e], d = dst[e];
        float xi = x[(size_t)d * 64 + lane];
        float xj = x[(size_t)s * 64 + lane];
        float dd = xj - xi;
        float u = b1j;
#pragma unroll
        for (int k = 0; k < 64; ++k) {
            u = fmaf(bcast(xi, k), w1a[k], u);
            u = fmaf(bcast(dd, k), w1b[k], u);
        }
        float h = leaky(u);
        float o = b2j;
#pragma unroll
        for (int k = 0; k < 64; ++k) o = fmaf(bcast(h, k), w2[k], o);
        atomicAdd(&raw[(size_t)d * 64 + lane], o);
    }
}

// ---------------- finalize: LN+leaky both convs, proj, leaky, global sum, candidate row ----------
__global__ void k_finalize(const float* __restrict__ dep_raw, const float* __restrict__ rev_raw,
                           const float* __restrict__ dg, const float* __restrict__ db,
                           const float* __restrict__ rg, const float* __restrict__ rb,
                           const float* __restrict__ PW, const float* __restrict__ pb,
                           float* __restrict__ out, float* __restrict__ gsum, int n_rows) {
    int lane = threadIdx.x & 63;
    int wid = threadIdx.x >> 6;
    int wave = (blockIdx.x * blockDim.x + threadIdx.x) >> 6;
    int nwaves = (gridDim.x * blockDim.x) >> 6;
    float p1[64], p2[64];
#pragma unroll
    for (int k = 0; k < 64; ++k) p1[k] = PW[k * 64 + lane];
#pragma unroll
    for (int k = 0; k < 64; ++k) p2[k] = PW[(64 + k) * 64 + lane];
    float pbj = pb[lane];
    float dgj = dg[lane], dbj = db[lane], rgj = rg[lane], rbj = rb[lane];
    float acc = 0.f;
    for (int r = wave; r < n_rows; r += nwaves) {
        float xd = dep_raw[(size_t)r * 64 + lane];
        float md = wsum(xd) * 0.015625f;
        float dd = xd - md;
        float vd = wsum(dd * dd) * 0.015625f;
        float dv = leaky(fmaf(dd * rsqrtf(vd + 1e-5f), dgj, dbj));
        float xr = rev_raw[(size_t)r * 64 + lane];
        float mr = wsum(xr) * 0.015625f;
        float dr = xr - mr;
        float vr = wsum(dr * dr) * 0.015625f;
        float rv = leaky(fmaf(dr * rsqrtf(vr + 1e-5f), rgj, rbj));
        float tf = pbj;
#pragma unroll
        for (int k = 0; k < 64; ++k) {
            tf = fmaf(bcast(dv, k), p1[k], tf);
            tf = fmaf(bcast(rv, k), p2[k], tf);
        }
        tf = leaky(tf);
        acc += tf;
        if (r == 0) out[64 + lane] = tf;
    }
    __shared__ float part[4][64];
    part[wid][lane] = acc;
    __syncthreads();
    if (wid == 0) {
        float ssum = part[0][lane] + part[1][lane] + part[2][lane] + part[3][lane];
        atomicAdd(&gsum[lane], ssum);
    }
}

// ---------------- tail: global_state normalize + device branch ----------------
__global__ void k_tail(const float* __restrict__ gsum, const int* __restrict__ counts,
                       const float* __restrict__ devx, const float* __restrict__ timex,
                       const float* __restrict__ dW, const float* __restrict__ dB,
                       float* __restrict__ out) {
    int j = threadIdx.x;
    if (j >= 64) return;
    int c = counts[0];
    if (c < 1) c = 1;
    out[j] = gsum[j] / (float)c;
    float t = timex[0] * 1e-5f;
    float acc = dB[j];
    for (int k = 0; k < 96; ++k) acc = fmaf(devx[k], dW[k * 64 + j], acc);
    acc = fmaf(t, dW[96 * 64 + j], acc);
    out[128 + j] = leaky(acc);
}

extern "C" void kernel_launch(void* const* d_in, const int* in_sizes, int n_in,
                              void* d_out, int out_size, void* d_ws, size_t ws_size,
                              hipStream_t stream) {
    const float* data_x    = (const float*)d_in[0];
    const float* tasks_x   = (const float*)d_in[1];
    const float* devices_x = (const float*)d_in[2];
    const float* time_x    = (const float*)d_in[3];
    const int*   dt_src    = (const int*)d_in[4];
    const int*   dt_dst    = (const int*)d_in[5];
    const int*   tt_src    = (const int*)d_in[6];
    const int*   tt_dst    = (const int*)d_in[7];
    const int*   counts    = (const int*)d_in[8];
    const float* gc_W_rel  = (const float*)d_in[9];
    const float* gc_b_rel  = (const float*)d_in[10];
    const float* gc_W_root = (const float*)d_in[11];
    const float* gc_ln_g   = (const float*)d_in[12];
    const float* gc_ln_b   = (const float*)d_in[13];
    const float* dep_W1    = (const float*)d_in[14];
    const float* dep_b1    = (const float*)d_in[15];
    const float* dep_W2    = (const float*)d_in[16];
    const float* dep_b2    = (const float*)d_in[17];
    const float* dep_ln_g  = (const float*)d_in[18];
    const float* dep_ln_b  = (const float*)d_in[19];
    const float* rev_W1    = (const float*)d_in[20];
    const float* rev_b1    = (const float*)d_in[21];
    const float* rev_W2    = (const float*)d_in[22];
    const float* rev_b2    = (const float*)d_in[23];
    const float* rev_ln_g  = (const float*)d_in[24];
    const float* rev_ln_b  = (const float*)d_in[25];
    const float* dev_W     = (const float*)d_in[26];
    const float* dev_b     = (const float*)d_in[27];
    const float* proj_W    = (const float*)d_in[28];
    const float* proj_b    = (const float*)d_in[29];

    int n_tasks = in_sizes[1] / 12;
    int n_dt = in_sizes[4];
    int n_tt = in_sizes[6];

    float* ws = (float*)d_ws;
    size_t off = 0;
    float* agg = ws + off;     off += (size_t)n_tasks * 5;  off = (off + 63) & ~(size_t)63;
    float* fused = ws + off;   off += (size_t)n_tasks * 64;
    float* dep_raw = ws + off; off += (size_t)n_tasks * 64;
    float* rev_raw = ws + off; off += (size_t)n_tasks * 64;
    float* gsum = ws + off;    off += 64;

    hipMemsetAsync(agg, 0, (size_t)n_tasks * 5 * sizeof(float), stream);
    hipMemsetAsync(dep_raw, 0, (size_t)n_tasks * 64 * sizeof(float), stream);
    hipMemsetAsync(rev_raw, 0, (size_t)n_tasks * 64 * sizeof(float), stream);
    hipMemsetAsync(gsum, 0, 64 * sizeof(float), stream);

    k_scatter<<<(n_dt + 255) / 256, 256, 0, stream>>>(data_x, dt_src, dt_dst, agg, n_dt);
    k_fused<<<2048, 256, 0, stream>>>(agg, tasks_x, gc_W_rel, gc_b_rel, gc_W_root,
                                      gc_ln_g, gc_ln_b, fused, n_tasks);
    k_edgeconv<<<2048, 256, 0, stream>>>(fused, tt_src, tt_dst,
                                         dep_W1, dep_b1, dep_W2, dep_b2, dep_raw, n_tt);
    k_edgeconv<<<2048, 256, 0, stream>>>(fused, tt_dst, tt_src,
                                         rev_W1, rev_b1, rev_W2, rev_b2, rev_raw, n_tt);
    k_finalize<<<2048, 256, 0, stream>>>(dep_raw, rev_raw, dep_ln_g, dep_ln_b,
                                         rev_ln_g, rev_ln_b, proj_W, proj_b,
                                         (float*)d_out, gsum, n_tasks);
    k_tail<<<1, 64, 0, stream>>>(gsum, counts, devices_x, time_x, dev_W, dev_b, (float*)d_out);
}

// Round 2
// 1156.934 us; speedup vs baseline: 2.0261x; 2.0261x over previous
//
#include <hip/hip_runtime.h>

#define DEVFN static __device__ __forceinline__

typedef __attribute__((ext_vector_type(8))) short short8;
typedef __attribute__((ext_vector_type(4))) float f32x4;

DEVFN float leaky(float x) { return x > 0.f ? x : 0.01f * x; }

DEVFN float bcast(float v, int lane) {
    return __int_as_float(__builtin_amdgcn_readlane(__float_as_int(v), lane));
}

DEVFN float wsum(float v) {
#pragma unroll
    for (int o = 32; o > 0; o >>= 1) v += __shfl_xor(v, o, 64);
    return v;
}

DEVFN unsigned short f2bf(float f) {
    unsigned u = __float_as_uint(f);
    unsigned r = (u + 0x7FFFu + ((u >> 16) & 1u)) >> 16;
    return (unsigned short)r;
}
DEVFN float bf2f(unsigned short h) { return __uint_as_float(((unsigned)h) << 16); }

// ---------------- scatter data_x into agg over dt edges ----------------
__global__ void k_scatter(const float* __restrict__ data_x,
                          const int* __restrict__ src, const int* __restrict__ dst,
                          float* __restrict__ agg, int n_edges) {
    int i = blockIdx.x * blockDim.x + threadIdx.x;
    if (i >= n_edges) return;
    int s = src[i], d = dst[i];
    const float* xp = data_x + (size_t)s * 5;
    float* ap = agg + (size_t)d * 5;
#pragma unroll
    for (int k = 0; k < 5; ++k) atomicAdd(ap + k, xp[k]);
}

// ---------------- fused = leaky(LN(agg@Wrel + brel + tasks@Wroot)) -> bf16 ----------------
__global__ void k_fused(const float* __restrict__ agg, const float* __restrict__ tasks_x,
                        const float* __restrict__ Wrel, const float* __restrict__ brel,
                        const float* __restrict__ Wroot,
                        const float* __restrict__ g, const float* __restrict__ b,
                        unsigned short* __restrict__ xh, int n_rows) {
    int lane = threadIdx.x & 63;
    int wave = (blockIdx.x * blockDim.x + threadIdx.x) >> 6;
    int nwaves = (gridDim.x * blockDim.x) >> 6;
    float wrel[5], wroot[12];
#pragma unroll
    for (int k = 0; k < 5; ++k) wrel[k] = Wrel[k * 64 + lane];
#pragma unroll
    for (int k = 0; k < 12; ++k) wroot[k] = Wroot[k * 64 + lane];
    float bj = brel[lane], gj = g[lane], bbj = b[lane];
    for (int r = wave; r < n_rows; r += nwaves) {
        float f = bj;
#pragma unroll
        for (int k = 0; k < 5; ++k) f = fmaf(agg[(size_t)r * 5 + k], wrel[k], f);
#pragma unroll
        for (int k = 0; k < 12; ++k) f = fmaf(tasks_x[(size_t)r * 12 + k], wroot[k], f);
        float m = wsum(f) * 0.015625f;
        float d = f - m;
        float v = wsum(d * d) * 0.015625f;
        float y = fmaf(d * rsqrtf(v + 1e-5f), gj, bbj);
        xh[(size_t)r * 64 + lane] = f2bf(leaky(y));
    }
}

// ---------------- precompute weight fragments (hi/lo bf16, per-lane MFMA layout) ------------
// Per conv: w1 frags [kk4][nt4][hl2] then w2 frags [wv2][nt4][hl2]; frag = 64 lanes x 8 ushorts.
// W1eff rows: r<64 -> W1[r]-W1[64+r] ; r>=64 -> W1[r]   (so A = [xi | xj])
__global__ void k_prepw(const float* __restrict__ W1d, const float* __restrict__ W2d,
                        const float* __restrict__ W1r, const float* __restrict__ W2r,
                        unsigned short* __restrict__ wf) {
    int lane = threadIdx.x;  // 64 threads
    int r16 = lane & 15, g = lane >> 4;
    for (int c = 0; c < 2; ++c) {
        const float* W1 = c ? W1r : W1d;
        const float* W2 = c ? W2r : W2d;
        unsigned short* out = wf + (size_t)c * 48 * 512;
        for (int kk = 0; kk < 4; ++kk)
            for (int nt = 0; nt < 4; ++nt) {
                int fr = (kk * 4 + nt) * 2;
                for (int j = 0; j < 8; ++j) {
                    int k = kk * 32 + g * 8 + j, col = nt * 16 + r16;
                    float v = (k < 64) ? (W1[k * 64 + col] - W1[(64 + k) * 64 + col])
                                       : W1[k * 64 + col];
                    unsigned short hi = f2bf(v);
                    unsigned short lo = f2bf(v - bf2f(hi));
                    out[(size_t)fr * 512 + lane * 8 + j] = hi;
                    out[(size_t)(fr + 1) * 512 + lane * 8 + j] = lo;
                }
            }
        for (int wv = 0; wv < 2; ++wv)
            for (int nt = 0; nt < 4; ++nt) {
                int fr = 32 + (wv * 4 + nt) * 2;
                for (int j = 0; j < 8; ++j) {
                    int k = wv * 32 + g * 8 + j, col = nt * 16 + r16;
                    float v = W2[k * 64 + col];
                    unsigned short hi = f2bf(v);
                    unsigned short lo = f2bf(v - bf2f(hi));
                    out[(size_t)fr * 512 + lane * 8 + j] = hi;
                    out[(size_t)(fr + 1) * 512 + lane * 8 + j] = lo;
                }
            }
    }
}

// ---------------- MFMA EdgeConv ----------------
// Block = 2 waves. Tile = 16 edges. Wave w owns layer-1 n-tiles {2w,2w+1} (its 32 H cols),
// then layer-2 partial-K over its own 32 H rows for all 4 n-tiles; partials merged via LDS.
__global__ void __launch_bounds__(128, 2) k_econv(
    const unsigned short* __restrict__ xh,
    const int* __restrict__ src, const int* __restrict__ dst,
    const unsigned short* __restrict__ wf,
    const float* __restrict__ b1, const float* __restrict__ b2,
    float* __restrict__ raw, int n_edges, int n_tiles) {
    __shared__ __align__(16) float ldsH[2][16][36];
    __shared__ float oex[16][64];
    int lane = threadIdx.x & 63;
    int w = threadIdx.x >> 6;
    int r16 = lane & 15, g = lane >> 4;

    short8 w1f[4][2][2];  // [kk][ntl][hl]
#pragma unroll
    for (int kk = 0; kk < 4; ++kk)
#pragma unroll
        for (int ntl = 0; ntl < 2; ++ntl)
#pragma unroll
            for (int hl = 0; hl < 2; ++hl) {
                int nt = w * 2 + ntl;
                w1f[kk][ntl][hl] =
                    *(const short8*)(wf + (size_t)((kk * 4 + nt) * 2 + hl) * 512 + lane * 8);
            }
    short8 w2f[4][2];  // [nt][hl]
#pragma unroll
    for (int nt = 0; nt < 4; ++nt)
#pragma unroll
        for (int hl = 0; hl < 2; ++hl)
            w2f[nt][hl] =
                *(const short8*)(wf + (size_t)(32 + (w * 4 + nt) * 2 + hl) * 512 + lane * 8);

    float b1v[2];
#pragma unroll
    for (int ntl = 0; ntl < 2; ++ntl) b1v[ntl] = b1[(w * 2 + ntl) * 16 + r16];
    float b2v[4];
#pragma unroll
    for (int nt = 0; nt < 4; ++nt) b2v[nt] = (w == 0) ? b2[nt * 16 + r16] : 0.f;

    for (int t = blockIdx.x; t < n_tiles; t += gridDim.x) {
        int e0 = t * 16;
        int ea = e0 + r16;
        ea = ea < n_edges ? ea : n_edges - 1;
        int ri = dst[ea], rj = src[ea];
        int dq[4];
#pragma unroll
        for (int q = 0; q < 4; ++q) {
            int eq = e0 + g * 4 + q;
            dq[q] = dst[eq < n_edges ? eq : n_edges - 1];
        }
        // gather A fragments (bf16 hi) straight into frag layout
        short8 af[4];
        af[0] = *(const short8*)(xh + (size_t)ri * 64 + g * 8);
        af[1] = *(const short8*)(xh + (size_t)ri * 64 + 32 + g * 8);
        af[2] = *(const short8*)(xh + (size_t)rj * 64 + g * 8);
        af[3] = *(const short8*)(xh + (size_t)rj * 64 + 32 + g * 8);

        // layer 1: this wave's 2 n-tiles, full K=128
        f32x4 acc[2];
#pragma unroll
        for (int ntl = 0; ntl < 2; ++ntl) acc[ntl] = (f32x4){b1v[ntl], b1v[ntl], b1v[ntl], b1v[ntl]};
#pragma unroll
        for (int kk = 0; kk < 4; ++kk)
#pragma unroll
            for (int ntl = 0; ntl < 2; ++ntl) {
                acc[ntl] = __builtin_amdgcn_mfma_f32_16x16x32_bf16(af[kk], w1f[kk][ntl][0],
                                                                   acc[ntl], 0, 0, 0);
                acc[ntl] = __builtin_amdgcn_mfma_f32_16x16x32_bf16(af[kk], w1f[kk][ntl][1],
                                                                   acc[ntl], 0, 0, 0);
            }
        // leaky + transpose own 32 H cols via wave-local LDS
#pragma unroll
        for (int ntl = 0; ntl < 2; ++ntl)
#pragma unroll
            for (int q = 0; q < 4; ++q)
                ldsH[w][g * 4 + q][ntl * 16 + r16] = leaky(acc[ntl][q]);
        __syncthreads();
        f32x4 h0 = *(const f32x4*)&ldsH[w][r16][g * 8];
        f32x4 h1 = *(const f32x4*)&ldsH[w][r16][g * 8 + 4];
        short8 hf;
#pragma unroll
        for (int j = 0; j < 4; ++j) {
            hf[j] = (short)f2bf(h0[j]);
            hf[4 + j] = (short)f2bf(h1[j]);
        }
        // layer 2: partial K (this wave's 32 H rows), all 4 n-tiles
        f32x4 acc2[4];
#pragma unroll
        for (int nt = 0; nt < 4; ++nt) acc2[nt] = (f32x4){b2v[nt], b2v[nt], b2v[nt], b2v[nt]};
#pragma unroll
        for (int nt = 0; nt < 4; ++nt) {
            acc2[nt] = __builtin_amdgcn_mfma_f32_16x16x32_bf16(hf, w2f[nt][0], acc2[nt], 0, 0, 0);
            acc2[nt] = __builtin_amdgcn_mfma_f32_16x16x32_bf16(hf, w2f[nt][1], acc2[nt], 0, 0, 0);
        }
        // merge wave1 partials into wave0, then scatter
        if (w == 1) {
#pragma unroll
            for (int nt = 0; nt < 4; ++nt)
#pragma unroll
                for (int q = 0; q < 4; ++q) oex[nt * 4 + q][lane] = acc2[nt][q];
        }
        __syncthreads();
        if (w == 0) {
#pragma unroll
            for (int nt = 0; nt < 4; ++nt)
#pragma unroll
                for (int q = 0; q < 4; ++q) {
                    int eq = e0 + g * 4 + q;
                    if (eq < n_edges) {
                        float val = acc2[nt][q] + oex[nt * 4 + q][lane];
                        atomicAdd(&raw[(size_t)dq[q] * 64 + nt * 16 + r16], val);
                    }
                }
        }
    }
}

// ---------------- finalize: LN+leaky both convs, proj, leaky, global sum, candidate row ----------
__global__ void k_finalize(const float* __restrict__ dep_raw, const float* __restrict__ rev_raw,
                           const float* __restrict__ dg, const float* __restrict__ db,
                           const float* __restrict__ rg, const float* __restrict__ rb,
                           const float* __restrict__ PW, const float* __restrict__ pb,
                           float* __restrict__ out, float* __restrict__ gsum, int n_rows) {
    int lane = threadIdx.x & 63;
    int wid = threadIdx.x >> 6;
    int wave = (blockIdx.x * blockDim.x + threadIdx.x) >> 6;
    int nwaves = (gridDim.x * blockDim.x) >> 6;
    float p1[64], p2[64];
#pragma unroll
    for (int k = 0; k < 64; ++k) p1[k] = PW[k * 64 + lane];
#pragma unroll
    for (int k = 0; k < 64; ++k) p2[k] = PW[(64 + k) * 64 + lane];
    float pbj = pb[lane];
    float dgj = dg[lane], dbj = db[lane], rgj = rg[lane], rbj = rb[lane];
    float acc = 0.f;
    for (int r = wave; r < n_rows; r += nwaves) {
        float xd = dep_raw[(size_t)r * 64 + lane];
        float md = wsum(xd) * 0.015625f;
        float dd = xd - md;
        float vd = wsum(dd * dd) * 0.015625f;
        float dv = leaky(fmaf(dd * rsqrtf(vd + 1e-5f), dgj, dbj));
        float xr = rev_raw[(size_t)r * 64 + lane];
        float mr = wsum(xr) * 0.015625f;
        float dr = xr - mr;
        float vr = wsum(dr * dr) * 0.015625f;
        float rv = leaky(fmaf(dr * rsqrtf(vr + 1e-5f), rgj, rbj));
        float tf = pbj;
#pragma unroll
        for (int k = 0; k < 64; ++k) {
            tf = fmaf(bcast(dv, k), p1[k], tf);
            tf = fmaf(bcast(rv, k), p2[k], tf);
        }
        tf = leaky(tf);
        acc += tf;
        if (r == 0) out[64 + lane] = tf;
    }
    __shared__ float part[4][64];
    part[wid][lane] = acc;
    __syncthreads();
    if (wid == 0) {
        float ssum = part[0][lane] + part[1][lane] + part[2][lane] + part[3][lane];
        atomicAdd(&gsum[lane], ssum);
    }
}

// ---------------- tail: global_state normalize + device branch ----------------
__global__ void k_tail(const float* __restrict__ gsum, const int* __restrict__ counts,
                       const float* __restrict__ devx, const float* __restrict__ timex,
                       const float* __restrict__ dW, const float* __restrict__ dB,
                       float* __restrict__ out) {
    int j = threadIdx.x;
    if (j >= 64) return;
    int c = counts[0];
    if (c < 1) c = 1;
    out[j] = gsum[j] / (float)c;
    float t = timex[0] * 1e-5f;
    float acc = dB[j];
    for (int k = 0; k < 96; ++k) acc = fmaf(devx[k], dW[k * 64 + j], acc);
    acc = fmaf(t, dW[96 * 64 + j], acc);
    out[128 + j] = leaky(acc);
}

extern "C" void kernel_launch(void* const* d_in, const int* in_sizes, int n_in,
                              void* d_out, int out_size, void* d_ws, size_t ws_size,
                              hipStream_t stream) {
    const float* data_x    = (const float*)d_in[0];
    const float* tasks_x   = (const float*)d_in[1];
    const float* devices_x = (const float*)d_in[2];
    const float* time_x    = (const float*)d_in[3];
    const int*   dt_src    = (const int*)d_in[4];
    const int*   dt_dst    = (const int*)d_in[5];
    const int*   tt_src    = (const int*)d_in[6];
    const int*   tt_dst    = (const int*)d_in[7];
    const int*   counts    = (const int*)d_in[8];
    const float* gc_W_rel  = (const float*)d_in[9];
    const float* gc_b_rel  = (const float*)d_in[10];
    const float* gc_W_root = (const float*)d_in[11];
    const float* gc_ln_g   = (const float*)d_in[12];
    const float* gc_ln_b   = (const float*)d_in[13];
    const float* dep_W1    = (const float*)d_in[14];
    const float* dep_b1    = (const float*)d_in[15];
    const float* dep_W2    = (const float*)d_in[16];
    const float* dep_b2    = (const float*)d_in[17];
    const float* dep_ln_g  = (const float*)d_in[18];
    const float* dep_ln_b  = (const float*)d_in[19];
    const float* rev_W1    = (const float*)d_in[20];
    const float* rev_b1    = (const float*)d_in[21];
    const float* rev_W2    = (const float*)d_in[22];
    const float* rev_b2    = (const float*)d_in[23];
    const float* rev_ln_g  = (const float*)d_in[24];
    const float* rev_ln_b  = (const float*)d_in[25];
    const float* dev_W     = (const float*)d_in[26];
    const float* dev_b     = (const float*)d_in[27];
    const float* proj_W    = (const float*)d_in[28];
    const float* proj_b    = (const float*)d_in[29];

    int n_tasks = in_sizes[1] / 12;
    int n_dt = in_sizes[4];
    int n_tt = in_sizes[6];
    int n_tiles = (n_tt + 15) / 16;

    char* ws = (char*)d_ws;
    size_t off = 0;
    auto alloc = [&](size_t bytes) {
        char* p = ws + off;
        off += (bytes + 255) & ~(size_t)255;
        return p;
    };
    float* agg            = (float*)alloc((size_t)n_tasks * 5 * 4);
    unsigned short* xh    = (unsigned short*)alloc((size_t)n_tasks * 64 * 2);
    float* dep_raw        = (float*)alloc((size_t)n_tasks * 64 * 4);
    float* rev_raw        = (float*)alloc((size_t)n_tasks * 64 * 4);
    float* gsum           = (float*)alloc(64 * 4);
    unsigned short* wfrag = (unsigned short*)alloc(2 * 48 * 512 * 2);

    hipMemsetAsync(agg, 0, (size_t)n_tasks * 5 * 4, stream);
    hipMemsetAsync(dep_raw, 0, (size_t)n_tasks * 64 * 4, stream);
    hipMemsetAsync(rev_raw, 0, (size_t)n_tasks * 64 * 4, stream);
    hipMemsetAsync(gsum, 0, 64 * 4, stream);

    k_prepw<<<1, 64, 0, stream>>>(dep_W1, dep_W2, rev_W1, rev_W2, wfrag);
    k_scatter<<<(n_dt + 255) / 256, 256, 0, stream>>>(data_x, dt_src, dt_dst, agg, n_dt);
    k_fused<<<2048, 256, 0, stream>>>(agg, tasks_x, gc_W_rel, gc_b_rel, gc_W_root,
                                      gc_ln_g, gc_ln_b, xh, n_tasks);
    k_econv<<<2048, 128, 0, stream>>>(xh, tt_src, tt_dst, wfrag,
                                      dep_b1, dep_b2, dep_raw, n_tt, n_tiles);
    k_econv<<<2048, 128, 0, stream>>>(xh, tt_dst, tt_src, wfrag + 48 * 512,
                                      rev_b1, rev_b2, rev_raw, n_tt, n_tiles);
    k_finalize<<<2048, 256, 0, stream>>>(dep_raw, rev_raw, dep_ln_g, dep_ln_b,
                                         rev_ln_g, rev_ln_b, proj_W, proj_b,
                                         (float*)d_out, gsum, n_tasks);
    k_tail<<<1, 64, 0, stream>>>(gsum, counts, devices_x, time_x, dev_W, dev_b, (float*)d_out);
}

// Round 3
// 958.556 us; speedup vs baseline: 2.4454x; 1.2070x over previous
//
#include <hip/hip_runtime.h>

#define DEVFN static __device__ __forceinline__

typedef __attribute__((ext_vector_type(8))) short short8;
typedef __attribute__((ext_vector_type(4))) float f32x4;

DEVFN float leaky(float x) { return x > 0.f ? x : 0.01f * x; }

DEVFN float wsum(float v) {
#pragma unroll
    for (int o = 32; o > 0; o >>= 1) v += __shfl_xor(v, o, 64);
    return v;
}

DEVFN unsigned short f2bf(float f) {
    unsigned u = __float_as_uint(f);
    unsigned r = (u + 0x7FFFu + ((u >> 16) & 1u)) >> 16;
    return (unsigned short)r;
}
DEVFN float bf2f(unsigned short h) { return __uint_as_float(((unsigned)h) << 16); }

// ---------------- scatter data_x into agg over dt edges ----------------
__global__ void k_scatter(const float* __restrict__ data_x,
                          const int* __restrict__ src, const int* __restrict__ dst,
                          float* __restrict__ agg, int n_edges) {
    int i = blockIdx.x * blockDim.x + threadIdx.x;
    if (i >= n_edges) return;
    int s = src[i], d = dst[i];
    const float* xp = data_x + (size_t)s * 5;
    float* ap = agg + (size_t)d * 5;
#pragma unroll
    for (int k = 0; k < 5; ++k) atomicAdd(ap + k, xp[k]);
}

// ---------------- fused = leaky(LN(agg@Wrel + brel + tasks@Wroot)) -> bf16 ----------------
__global__ void k_fused(const float* __restrict__ agg, const float* __restrict__ tasks_x,
                        const float* __restrict__ Wrel, const float* __restrict__ brel,
                        const float* __restrict__ Wroot,
                        const float* __restrict__ g, const float* __restrict__ b,
                        unsigned short* __restrict__ xh, int n_rows) {
    int lane = threadIdx.x & 63;
    int wave = (blockIdx.x * blockDim.x + threadIdx.x) >> 6;
    int nwaves = (gridDim.x * blockDim.x) >> 6;
    float wrel[5], wroot[12];
#pragma unroll
    for (int k = 0; k < 5; ++k) wrel[k] = Wrel[k * 64 + lane];
#pragma unroll
    for (int k = 0; k < 12; ++k) wroot[k] = Wroot[k * 64 + lane];
    float bj = brel[lane], gj = g[lane], bbj = b[lane];
    for (int r = wave; r < n_rows; r += nwaves) {
        float f = bj;
#pragma unroll
        for (int k = 0; k < 5; ++k) f = fmaf(agg[(size_t)r * 5 + k], wrel[k], f);
#pragma unroll
        for (int k = 0; k < 12; ++k) f = fmaf(tasks_x[(size_t)r * 12 + k], wroot[k], f);
        float m = wsum(f) * 0.015625f;
        float d = f - m;
        float v = wsum(d * d) * 0.015625f;
        float y = fmaf(d * rsqrtf(v + 1e-5f), gj, bbj);
        xh[(size_t)r * 64 + lane] = f2bf(leaky(y));
    }
}

// ---------------- precompute weight fragments (hi/lo bf16, per-lane MFMA layout) ------------
// conv c in {0,1}: 48 frags each (w1: [kk4][nt4][hl2] = 32, w2: [wv2][nt4][hl2] = 16)
// then proj: 32 frags [kk4][nt4][hl2].  frag = 64 lanes x 8 ushorts.
__global__ void k_prepw(const float* __restrict__ W1d, const float* __restrict__ W2d,
                        const float* __restrict__ W1r, const float* __restrict__ W2r,
                        const float* __restrict__ PW,
                        unsigned short* __restrict__ wf) {
    int lane = threadIdx.x;  // 64 threads
    int r16 = lane & 15, g = lane >> 4;
    for (int c = 0; c < 2; ++c) {
        const float* W1 = c ? W1r : W1d;
        const float* W2 = c ? W2r : W2d;
        unsigned short* out = wf + (size_t)c * 48 * 512;
        for (int kk = 0; kk < 4; ++kk)
            for (int nt = 0; nt < 4; ++nt) {
                int fr = (kk * 4 + nt) * 2;
                for (int j = 0; j < 8; ++j) {
                    int k = kk * 32 + g * 8 + j, col = nt * 16 + r16;
                    float v = (k < 64) ? (W1[k * 64 + col] - W1[(64 + k) * 64 + col])
                                       : W1[k * 64 + col];
                    unsigned short hi = f2bf(v);
                    unsigned short lo = f2bf(v - bf2f(hi));
                    out[(size_t)fr * 512 + lane * 8 + j] = hi;
                    out[(size_t)(fr + 1) * 512 + lane * 8 + j] = lo;
                }
            }
        for (int wv = 0; wv < 2; ++wv)
            for (int nt = 0; nt < 4; ++nt) {
                int fr = 32 + (wv * 4 + nt) * 2;
                for (int j = 0; j < 8; ++j) {
                    int k = wv * 32 + g * 8 + j, col = nt * 16 + r16;
                    float v = W2[k * 64 + col];
                    unsigned short hi = f2bf(v);
                    unsigned short lo = f2bf(v - bf2f(hi));
                    out[(size_t)fr * 512 + lane * 8 + j] = hi;
                    out[(size_t)(fr + 1) * 512 + lane * 8 + j] = lo;
                }
            }
    }
    {
        unsigned short* out = wf + (size_t)2 * 48 * 512;
        for (int kk = 0; kk < 4; ++kk)
            for (int nt = 0; nt < 4; ++nt) {
                int fr = (kk * 4 + nt) * 2;
                for (int j = 0; j < 8; ++j) {
                    int k = kk * 32 + g * 8 + j, col = nt * 16 + r16;
                    float v = PW[k * 64 + col];
                    unsigned short hi = f2bf(v);
                    unsigned short lo = f2bf(v - bf2f(hi));
                    out[(size_t)fr * 512 + lane * 8 + j] = hi;
                    out[(size_t)(fr + 1) * 512 + lane * 8 + j] = lo;
                }
            }
    }
}

// ---------------- MFMA EdgeConv ----------------
__global__ void __launch_bounds__(128, 2) k_econv(
    const unsigned short* __restrict__ xh,
    const int* __restrict__ src, const int* __restrict__ dst,
    const unsigned short* __restrict__ wf,
    const float* __restrict__ b1, const float* __restrict__ b2,
    float* __restrict__ raw, int n_edges, int n_tiles) {
    __shared__ __align__(16) float ldsH[2][16][36];
    __shared__ float oex[16][64];
    int lane = threadIdx.x & 63;
    int w = threadIdx.x >> 6;
    int r16 = lane & 15, g = lane >> 4;

    short8 w1f[4][2][2];
#pragma unroll
    for (int kk = 0; kk < 4; ++kk)
#pragma unroll
        for (int ntl = 0; ntl < 2; ++ntl)
#pragma unroll
            for (int hl = 0; hl < 2; ++hl) {
                int nt = w * 2 + ntl;
                w1f[kk][ntl][hl] =
                    *(const short8*)(wf + (size_t)((kk * 4 + nt) * 2 + hl) * 512 + lane * 8);
            }
    short8 w2f[4][2];
#pragma unroll
    for (int nt = 0; nt < 4; ++nt)
#pragma unroll
        for (int hl = 0; hl < 2; ++hl)
            w2f[nt][hl] =
                *(const short8*)(wf + (size_t)(32 + (w * 4 + nt) * 2 + hl) * 512 + lane * 8);

    float b1v[2];
#pragma unroll
    for (int ntl = 0; ntl < 2; ++ntl) b1v[ntl] = b1[(w * 2 + ntl) * 16 + r16];
    float b2v[4];
#pragma unroll
    for (int nt = 0; nt < 4; ++nt) b2v[nt] = (w == 0) ? b2[nt * 16 + r16] : 0.f;

    for (int t = blockIdx.x; t < n_tiles; t += gridDim.x) {
        int e0 = t * 16;
        int ea = e0 + r16;
        ea = ea < n_edges ? ea : n_edges - 1;
        int ri = dst[ea], rj = src[ea];
        int dq[4];
#pragma unroll
        for (int q = 0; q < 4; ++q) {
            int eq = e0 + g * 4 + q;
            dq[q] = dst[eq < n_edges ? eq : n_edges - 1];
        }
        short8 af[4];
        af[0] = *(const short8*)(xh + (size_t)ri * 64 + g * 8);
        af[1] = *(const short8*)(xh + (size_t)ri * 64 + 32 + g * 8);
        af[2] = *(const short8*)(xh + (size_t)rj * 64 + g * 8);
        af[3] = *(const short8*)(xh + (size_t)rj * 64 + 32 + g * 8);

        f32x4 acc[2];
#pragma unroll
        for (int ntl = 0; ntl < 2; ++ntl) acc[ntl] = (f32x4){b1v[ntl], b1v[ntl], b1v[ntl], b1v[ntl]};
#pragma unroll
        for (int kk = 0; kk < 4; ++kk)
#pragma unroll
            for (int ntl = 0; ntl < 2; ++ntl) {
                acc[ntl] = __builtin_amdgcn_mfma_f32_16x16x32_bf16(af[kk], w1f[kk][ntl][0],
                                                                   acc[ntl], 0, 0, 0);
                acc[ntl] = __builtin_amdgcn_mfma_f32_16x16x32_bf16(af[kk], w1f[kk][ntl][1],
                                                                   acc[ntl], 0, 0, 0);
            }
#pragma unroll
        for (int ntl = 0; ntl < 2; ++ntl)
#pragma unroll
            for (int q = 0; q < 4; ++q)
                ldsH[w][g * 4 + q][ntl * 16 + r16] = leaky(acc[ntl][q]);
        __syncthreads();
        f32x4 h0 = *(const f32x4*)&ldsH[w][r16][g * 8];
        f32x4 h1 = *(const f32x4*)&ldsH[w][r16][g * 8 + 4];
        short8 hf;
#pragma unroll
        for (int j = 0; j < 4; ++j) {
            hf[j] = (short)f2bf(h0[j]);
            hf[4 + j] = (short)f2bf(h1[j]);
        }
        f32x4 acc2[4];
#pragma unroll
        for (int nt = 0; nt < 4; ++nt) acc2[nt] = (f32x4){b2v[nt], b2v[nt], b2v[nt], b2v[nt]};
#pragma unroll
        for (int nt = 0; nt < 4; ++nt) {
            acc2[nt] = __builtin_amdgcn_mfma_f32_16x16x32_bf16(hf, w2f[nt][0], acc2[nt], 0, 0, 0);
            acc2[nt] = __builtin_amdgcn_mfma_f32_16x16x32_bf16(hf, w2f[nt][1], acc2[nt], 0, 0, 0);
        }
        if (w == 1) {
#pragma unroll
            for (int nt = 0; nt < 4; ++nt)
#pragma unroll
                for (int q = 0; q < 4; ++q) oex[nt * 4 + q][lane] = acc2[nt][q];
        }
        __syncthreads();
        if (w == 0) {
#pragma unroll
            for (int nt = 0; nt < 4; ++nt)
#pragma unroll
                for (int q = 0; q < 4; ++q) {
                    int eq = e0 + g * 4 + q;
                    if (eq < n_edges) {
                        float val = acc2[nt][q] + oex[nt * 4 + q][lane];
                        atomicAdd(&raw[(size_t)dq[q] * 64 + nt * 16 + r16], val);
                    }
                }
        }
    }
}

// ---------------- finalize (MFMA): LN+leaky both convs, proj, leaky, gsum, candidate ----------
__global__ void __launch_bounds__(256, 2) k_finalize(
    const float* __restrict__ dep_raw, const float* __restrict__ rev_raw,
    const float* __restrict__ dg, const float* __restrict__ db,
    const float* __restrict__ rg, const float* __restrict__ rb,
    const unsigned short* __restrict__ pwf, const float* __restrict__ pb,
    float* __restrict__ out, float* __restrict__ gsum, int n_rows, int n_tiles) {
    __shared__ float red[4][64];
    int lane = threadIdx.x & 63;
    int wid = threadIdx.x >> 6;
    int r16 = lane & 15, g = lane >> 4;
    int wave = (blockIdx.x * blockDim.x + threadIdx.x) >> 6;
    int nwaves = (gridDim.x * blockDim.x) >> 6;

    short8 wf[4][4][2];
#pragma unroll
    for (int kk = 0; kk < 4; ++kk)
#pragma unroll
        for (int nt = 0; nt < 4; ++nt)
#pragma unroll
            for (int hl = 0; hl < 2; ++hl)
                wf[kk][nt][hl] =
                    *(const short8*)(pwf + (size_t)((kk * 4 + nt) * 2 + hl) * 512 + lane * 8);

    // per-lane LN params: dep cols {g*8+j, 32+g*8+j}, rev same indices
    f32x4 gd0 = *(const f32x4*)(dg + g * 8), gd1 = *(const f32x4*)(dg + g * 8 + 4);
    f32x4 gd2 = *(const f32x4*)(dg + 32 + g * 8), gd3 = *(const f32x4*)(dg + 32 + g * 8 + 4);
    f32x4 bd0 = *(const f32x4*)(db + g * 8), bd1 = *(const f32x4*)(db + g * 8 + 4);
    f32x4 bd2 = *(const f32x4*)(db + 32 + g * 8), bd3 = *(const f32x4*)(db + 32 + g * 8 + 4);
    f32x4 gr0 = *(const f32x4*)(rg + g * 8), gr1 = *(const f32x4*)(rg + g * 8 + 4);
    f32x4 gr2 = *(const f32x4*)(rg + 32 + g * 8), gr3 = *(const f32x4*)(rg + 32 + g * 8 + 4);
    f32x4 br0 = *(const f32x4*)(rb + g * 8), br1 = *(const f32x4*)(rb + g * 8 + 4);
    f32x4 br2 = *(const f32x4*)(rb + 32 + g * 8), br3 = *(const f32x4*)(rb + 32 + g * 8 + 4);

    float b2v[4];
#pragma unroll
    for (int nt = 0; nt < 4; ++nt) b2v[nt] = pb[nt * 16 + r16];
    float gacc[4] = {0.f, 0.f, 0.f, 0.f};

    for (int t = wave; t < n_tiles; t += nwaves) {
        int r0 = t * 16;
        int ra = r0 + r16;
        ra = ra < n_rows ? ra : n_rows - 1;
        const float* dp = dep_raw + (size_t)ra * 64;
        const float* rp = rev_raw + (size_t)ra * 64;
        f32x4 xd0 = *(const f32x4*)(dp + g * 8);
        f32x4 xd1 = *(const f32x4*)(dp + g * 8 + 4);
        f32x4 xd2 = *(const f32x4*)(dp + 32 + g * 8);
        f32x4 xd3 = *(const f32x4*)(dp + 32 + g * 8 + 4);
        f32x4 xr0 = *(const f32x4*)(rp + g * 8);
        f32x4 xr1 = *(const f32x4*)(rp + g * 8 + 4);
        f32x4 xr2 = *(const f32x4*)(rp + 32 + g * 8);
        f32x4 xr3 = *(const f32x4*)(rp + 32 + g * 8 + 4);

        float sd = 0.f, qd = 0.f, sr = 0.f, qr = 0.f;
#pragma unroll
        for (int j = 0; j < 4; ++j) {
            sd += xd0[j] + xd1[j] + xd2[j] + xd3[j];
            qd = fmaf(xd0[j], xd0[j], qd); qd = fmaf(xd1[j], xd1[j], qd);
            qd = fmaf(xd2[j], xd2[j], qd); qd = fmaf(xd3[j], xd3[j], qd);
            sr += xr0[j] + xr1[j] + xr2[j] + xr3[j];
            qr = fmaf(xr0[j], xr0[j], qr); qr = fmaf(xr1[j], xr1[j], qr);
            qr = fmaf(xr2[j], xr2[j], qr); qr = fmaf(xr3[j], xr3[j], qr);
        }
#pragma unroll
        for (int o = 16; o <= 32; o <<= 1) {
            sd += __shfl_xor(sd, o, 64); qd += __shfl_xor(qd, o, 64);
            sr += __shfl_xor(sr, o, 64); qr += __shfl_xor(qr, o, 64);
        }
        float md = sd * 0.015625f;
        float rstd_d = rsqrtf(fmaf(qd, 0.015625f, -md * md) + 1e-5f);
        float mr = sr * 0.015625f;
        float rstd_r = rsqrtf(fmaf(qr, 0.015625f, -mr * mr) + 1e-5f);

        short8 af[4];
#pragma unroll
        for (int j = 0; j < 4; ++j) {
            af[0][j]     = (short)f2bf(leaky(fmaf((xd0[j] - md) * rstd_d, gd0[j], bd0[j])));
            af[0][4 + j] = (short)f2bf(leaky(fmaf((xd1[j] - md) * rstd_d, gd1[j], bd1[j])));
            af[1][j]     = (short)f2bf(leaky(fmaf((xd2[j] - md) * rstd_d, gd2[j], bd2[j])));
            af[1][4 + j] = (short)f2bf(leaky(fmaf((xd3[j] - md) * rstd_d, gd3[j], bd3[j])));
            af[2][j]     = (short)f2bf(leaky(fmaf((xr0[j] - mr) * rstd_r, gr0[j], br0[j])));
            af[2][4 + j] = (short)f2bf(leaky(fmaf((xr1[j] - mr) * rstd_r, gr1[j], br1[j])));
            af[3][j]     = (short)f2bf(leaky(fmaf((xr2[j] - mr) * rstd_r, gr2[j], br2[j])));
            af[3][4 + j] = (short)f2bf(leaky(fmaf((xr3[j] - mr) * rstd_r, gr3[j], br3[j])));
        }

        f32x4 acc[4];
#pragma unroll
        for (int nt = 0; nt < 4; ++nt) acc[nt] = (f32x4){b2v[nt], b2v[nt], b2v[nt], b2v[nt]};
#pragma unroll
        for (int kk = 0; kk < 4; ++kk)
#pragma unroll
            for (int nt = 0; nt < 4; ++nt) {
                acc[nt] = __builtin_amdgcn_mfma_f32_16x16x32_bf16(af[kk], wf[kk][nt][0],
                                                                  acc[nt], 0, 0, 0);
                acc[nt] = __builtin_amdgcn_mfma_f32_16x16x32_bf16(af[kk], wf[kk][nt][1],
                                                                  acc[nt], 0, 0, 0);
            }
#pragma unroll
        for (int nt = 0; nt < 4; ++nt)
#pragma unroll
            for (int q = 0; q < 4; ++q) {
                float tf = leaky(acc[nt][q]);
                int grow = r0 + g * 4 + q;
                if (grow < n_rows) gacc[nt] += tf;
                if (grow == 0) out[64 + nt * 16 + r16] = tf;
            }
    }
#pragma unroll
    for (int nt = 0; nt < 4; ++nt) {
        gacc[nt] += __shfl_xor(gacc[nt], 16, 64);
        gacc[nt] += __shfl_xor(gacc[nt], 32, 64);
    }
    if (g == 0) {
#pragma unroll
        for (int nt = 0; nt < 4; ++nt) red[wid][nt * 16 + r16] = gacc[nt];
    }
    __syncthreads();
    if (threadIdx.x < 64) {
        float ssum = red[0][threadIdx.x] + red[1][threadIdx.x] +
                     red[2][threadIdx.x] + red[3][threadIdx.x];
        atomicAdd(&gsum[threadIdx.x], ssum);
    }
}

// ---------------- tail: global_state normalize + device branch ----------------
__global__ void k_tail(const float* __restrict__ gsum, const int* __restrict__ counts,
                       const float* __restrict__ devx, const float* __restrict__ timex,
                       const float* __restrict__ dW, const float* __restrict__ dB,
                       float* __restrict__ out) {
    int j = threadIdx.x;
    if (j >= 64) return;
    int c = counts[0];
    if (c < 1) c = 1;
    out[j] = gsum[j] / (float)c;
    float t = timex[0] * 1e-5f;
    float acc = dB[j];
    for (int k = 0; k < 96; ++k) acc = fmaf(devx[k], dW[k * 64 + j], acc);
    acc = fmaf(t, dW[96 * 64 + j], acc);
    out[128 + j] = leaky(acc);
}

extern "C" void kernel_launch(void* const* d_in, const int* in_sizes, int n_in,
                              void* d_out, int out_size, void* d_ws, size_t ws_size,
                              hipStream_t stream) {
    const float* data_x    = (const float*)d_in[0];
    const float* tasks_x   = (const float*)d_in[1];
    const float* devices_x = (const float*)d_in[2];
    const float* time_x    = (const float*)d_in[3];
    const int*   dt_src    = (const int*)d_in[4];
    const int*   dt_dst    = (const int*)d_in[5];
    const int*   tt_src    = (const int*)d_in[6];
    const int*   tt_dst    = (const int*)d_in[7];
    const int*   counts    = (const int*)d_in[8];
    const float* gc_W_rel  = (const float*)d_in[9];
    const float* gc_b_rel  = (const float*)d_in[10];
    const float* gc_W_root = (const float*)d_in[11];
    const float* gc_ln_g   = (const float*)d_in[12];
    const float* gc_ln_b   = (const float*)d_in[13];
    const float* dep_W1    = (const float*)d_in[14];
    const float* dep_b1    = (const float*)d_in[15];
    const float* dep_W2    = (const float*)d_in[16];
    const float* dep_b2    = (const float*)d_in[17];
    const float* dep_ln_g  = (const float*)d_in[18];
    const float* dep_ln_b  = (const float*)d_in[19];
    const float* rev_W1    = (const float*)d_in[20];
    const float* rev_b1    = (const float*)d_in[21];
    const float* rev_W2    = (const float*)d_in[22];
    const float* rev_b2    = (const float*)d_in[23];
    const float* rev_ln_g  = (const float*)d_in[24];
    const float* rev_ln_b  = (const float*)d_in[25];
    const float* dev_W     = (const float*)d_in[26];
    const float* dev_b     = (const float*)d_in[27];
    const float* proj_W    = (const float*)d_in[28];
    const float* proj_b    = (const float*)d_in[29];

    int n_tasks = in_sizes[1] / 12;
    int n_dt = in_sizes[4];
    int n_tt = in_sizes[6];
    int n_tiles = (n_tt + 15) / 16;
    int n_ftiles = (n_tasks + 15) / 16;

    char* ws = (char*)d_ws;
    size_t off = 0;
    auto alloc = [&](size_t bytes) {
        char* p = ws + off;
        off += (bytes + 255) & ~(size_t)255;
        return p;
    };
    float* agg            = (float*)alloc((size_t)n_tasks * 5 * 4);
    unsigned short* xh    = (unsigned short*)alloc((size_t)n_tasks * 64 * 2);
    float* dep_raw        = (float*)alloc((size_t)n_tasks * 64 * 4);
    float* rev_raw        = (float*)alloc((size_t)n_tasks * 64 * 4);
    float* gsum           = (float*)alloc(64 * 4);
    unsigned short* wfrag = (unsigned short*)alloc((2 * 48 + 32) * 512 * 2);

    hipMemsetAsync(agg, 0, (size_t)n_tasks * 5 * 4, stream);
    hipMemsetAsync(dep_raw, 0, (size_t)n_tasks * 64 * 4, stream);
    hipMemsetAsync(rev_raw, 0, (size_t)n_tasks * 64 * 4, stream);
    hipMemsetAsync(gsum, 0, 64 * 4, stream);

    k_prepw<<<1, 64, 0, stream>>>(dep_W1, dep_W2, rev_W1, rev_W2, proj_W, wfrag);
    k_scatter<<<(n_dt + 255) / 256, 256, 0, stream>>>(data_x, dt_src, dt_dst, agg, n_dt);
    k_fused<<<2048, 256, 0, stream>>>(agg, tasks_x, gc_W_rel, gc_b_rel, gc_W_root,
                                      gc_ln_g, gc_ln_b, xh, n_tasks);
    k_econv<<<2048, 128, 0, stream>>>(xh, tt_src, tt_dst, wfrag,
                                      dep_b1, dep_b2, dep_raw, n_tt, n_tiles);
    k_econv<<<2048, 128, 0, stream>>>(xh, tt_dst, tt_src, wfrag + 48 * 512,
                                      rev_b1, rev_b2, rev_raw, n_tt, n_tiles);
    k_finalize<<<2048, 256, 0, stream>>>(dep_raw, rev_raw, dep_ln_g, dep_ln_b,
                                         rev_ln_g, rev_ln_b, wfrag + 2 * 48 * 512, proj_b,
                                         (float*)d_out, gsum, n_tasks, n_ftiles);
    k_tail<<<1, 64, 0, stream>>>(gsum, counts, devices_x, time_x, dev_W, dev_b, (float*)d_out);
}